// Round 8
// baseline (559.425 us; speedup 1.0000x reference)
//
#include <hip/hip_runtime.h>

#define NSEQ   4096
#define TSTEPS 512
#define FIN    5
#define HID    64
#define SPB    16     // sequences per block (MFMA M)
#define BLK    512    // 8 waves: 0-3 MFMA-only (producer), 4-7 epilogue-only (consumer)

// Neutral names — do NOT reuse HIP vector-type names like short8 (R4 crash)
typedef __attribute__((ext_vector_type(8))) short bsh8;    // 8 bf16 in 4 VGPRs
typedef __attribute__((ext_vector_type(4))) float f32x4;   // MFMA accumulator

#define MFMA16(A, B, C) __builtin_amdgcn_mfma_f32_16x16x32_bf16((A), (B), (C), 0, 0, 0)

struct Frag2 { bsh8 hi; bsh8 lo; };

__device__ __forceinline__ unsigned short bf16hi_rn(float x) {
    unsigned u = __float_as_uint(x);
    return (unsigned short)((u + 0x7fffu + ((u >> 16) & 1u)) >> 16);
}
__device__ __forceinline__ void split_bf16(float v, unsigned short& h, unsigned short& l) {
    h = bf16hi_rn(v);
    float hf = __uint_as_float(((unsigned)h) << 16);
    l = bf16hi_rn(v - hf);
}

__device__ __forceinline__ float fast_sigmoid(float x) {
    return __builtin_amdgcn_rcpf(1.0f + __expf(-x));
}
__device__ __forceinline__ float fast_tanh(float x) {
    return 1.0f - 2.0f * __builtin_amdgcn_rcpf(1.0f + __expf(2.0f * x));
}

// B-fragment (weights SPLIT hi/lo — systematic weight error stays ~2^-17)
__device__ __forceinline__ Frag2 load_whh_frag(const float* __restrict__ Whh, int gate, int k) {
    const float* p = Whh + gate * HID + k;
    Frag2 r;
#pragma unroll
    for (int j = 0; j < 8; ++j) {
        unsigned short h, l;
        split_bf16(p[j], h, l);
        r.hi[j] = (short)h; r.lo[j] = (short)l;
    }
    return r;
}
__device__ __forceinline__ Frag2 load_wih_frag(const float* __restrict__ Wih, int gate, int quad) {
    Frag2 r;
#pragma unroll
    for (int j = 0; j < 8; ++j) { r.hi[j] = 0; r.lo[j] = 0; }
    if (quad == 0) {
#pragma unroll
        for (int j = 0; j < FIN; ++j) {
            unsigned short h, l;
            split_bf16(Wih[gate * FIN + j], h, l);
            r.hi[j] = (short)h; r.lo[j] = (short)l;
        }
    }
    return r;
}

// Producer/consumer MFMA LSTM. Per step:
//   phase1: MFMA waves: 16 h-MFMAs -> gate preacts (fp32) to LDS; epi waves
//           idle (or staging the next 64-step x chunk once per 64 steps)
//   [barrier]
//   phase2: epi waves: bias+activations+c/h update, h(bf16)->LDS; MFMA waves
//           pre-compute x-part of step t+1 (8 MFMAs, independent of h)
//   [barrier]
// No duplicated MFMAs (R7 lesson: one 16x16x32 bf16 MFMA = ~16 SIMD-cyc, so
// redundant pairing doubled the matrix-pipe load and regressed). Two waves
// per SIMD fill each other's latency stalls without adding work.
__global__ __launch_bounds__(BLK)
void lstm_kernel(const float* __restrict__ feat,
                 const float* __restrict__ Wih,
                 const float* __restrict__ Whh,
                 const float* __restrict__ bih,
                 const float* __restrict__ bhh,
                 const float* __restrict__ Wd,
                 const float* __restrict__ bd,
                 float* __restrict__ pred,
                 float* __restrict__ accums) {
    __shared__ bsh8  aA[2][SPB][9];       // h bf16, double-buffered (4.6 KB)
    __shared__ bsh8  xb[2][64][SPB];      // x bf16, chunk double buffer (32 KB)
    __shared__ float gt[4][SPB][HID + 4]; // gate preacts [gate][seq][unit] (17.4 KB)
    __shared__ float hf[SPB][HID + 1];    // final h fp32 for pred tail
    __shared__ float pf[SPB][17];         // pred partials

    const int tid   = threadIdx.x;
    const int w     = tid >> 6;           // wave 0..7
    const int lane  = tid & 63;
    const bool is_m = (w < 4);            // producer (MFMA) wave?
    const int col   = lane & 15;          // MFMA col / A-row (seq)
    const int quad  = lane >> 4;
    const int u_m   = 16 * (w & 3) + col; // MFMA-wave unit
    const int e     = w - 4;              // epi wave index 0..3 (seqs 4e..4e+3)
    const int seq0  = blockIdx.x * SPB;

    if (blockIdx.x == 0 && tid < 4) accums[tid] = 0.0f;   // loss accumulators

    // ---- persistent B fragments (MFMA waves; named structs — R1/R2 lessons) ----
    const int g0 = 0 * HID + u_m, g1 = 1 * HID + u_m,
              g2 = 2 * HID + u_m, g3 = 3 * HID + u_m;
    Frag2 b00 = load_whh_frag(Whh, g0, quad * 8);
    Frag2 b01 = load_whh_frag(Whh, g0, 32 + quad * 8);
    Frag2 b02 = load_wih_frag(Wih, g0, quad);
    Frag2 b10 = load_whh_frag(Whh, g1, quad * 8);
    Frag2 b11 = load_whh_frag(Whh, g1, 32 + quad * 8);
    Frag2 b12 = load_wih_frag(Wih, g1, quad);
    Frag2 b20 = load_whh_frag(Whh, g2, quad * 8);
    Frag2 b21 = load_whh_frag(Whh, g2, 32 + quad * 8);
    Frag2 b22 = load_wih_frag(Wih, g2, quad);
    Frag2 b30 = load_whh_frag(Whh, g3, quad * 8);
    Frag2 b31 = load_whh_frag(Whh, g3, 32 + quad * 8);
    Frag2 b32 = load_wih_frag(Wih, g3, quad);

    // epi-wave biases (per unit = lane)
    const float bi  = bih[0 * HID + lane] + bhh[0 * HID + lane];
    const float bf_ = bih[1 * HID + lane] + bhh[1 * HID + lane];
    const float bg  = bih[2 * HID + lane] + bhh[2 * HID + lane];
    const float bo  = bih[3 * HID + lane] + bhh[3 * HID + lane];

    // zero h buffer 0 (144 vectors)
    {
        bsh8 z = {0, 0, 0, 0, 0, 0, 0, 0};
        if (tid < SPB * 9) (&aA[0][0][0])[tid] = z;
    }
    // stage chunk 0 with all 512 threads
#pragma unroll
    for (int it = 0; it < (64 * SPB) / BLK; ++it) {
        int idx = tid + it * BLK;
        int t2  = idx >> 4;
        int s   = idx & 15;
        const float* xp = feat + (size_t)(seq0 + s) * (TSTEPS * FIN) + t2 * FIN;
        bsh8 v = {0, 0, 0, 0, 0, 0, 0, 0};
#pragma unroll
        for (int j = 0; j < FIN; ++j) v[j] = (short)bf16hi_rn(xp[j]);
        xb[0][t2][s] = v;
    }
    __syncthreads();

    // MFMA waves: acc := x-part of step 0 (bias added by epi waves)
    f32x4 acc0 = {0.f, 0.f, 0.f, 0.f};
    f32x4 acc1 = {0.f, 0.f, 0.f, 0.f};
    f32x4 acc2 = {0.f, 0.f, 0.f, 0.f};
    f32x4 acc3 = {0.f, 0.f, 0.f, 0.f};
    if (is_m) {
        bsh8 ax = xb[0][0][col];
        acc0 = MFMA16(ax, b02.hi, acc0); acc0 = MFMA16(ax, b02.lo, acc0);
        acc1 = MFMA16(ax, b12.hi, acc1); acc1 = MFMA16(ax, b12.lo, acc1);
        acc2 = MFMA16(ax, b22.hi, acc2); acc2 = MFMA16(ax, b22.lo, acc2);
        acc3 = MFMA16(ax, b32.hi, acc3); acc3 = MFMA16(ax, b32.lo, acc3);
    }

    float c_[4] = {0.f, 0.f, 0.f, 0.f};   // epi waves: c for seqs 4e..4e+3

    for (int t = 0; t < TSTEPS; ++t) {
        const int tt  = t & 63;
        const int buf = t & 1;
        const int nb  = buf ^ 1;

        // ---- phase 1 ----
        if (is_m) {
            bsh8 ah0 = aA[buf][col][quad];
            bsh8 ah1 = aA[buf][col][4 + quad];
            acc0 = MFMA16(ah0, b00.hi, acc0); acc0 = MFMA16(ah1, b01.hi, acc0);
            acc1 = MFMA16(ah0, b10.hi, acc1); acc1 = MFMA16(ah1, b11.hi, acc1);
            acc2 = MFMA16(ah0, b20.hi, acc2); acc2 = MFMA16(ah1, b21.hi, acc2);
            acc3 = MFMA16(ah0, b30.hi, acc3); acc3 = MFMA16(ah1, b31.hi, acc3);
            acc0 = MFMA16(ah0, b00.lo, acc0); acc0 = MFMA16(ah1, b01.lo, acc0);
            acc1 = MFMA16(ah0, b10.lo, acc1); acc1 = MFMA16(ah1, b11.lo, acc1);
            acc2 = MFMA16(ah0, b20.lo, acc2); acc2 = MFMA16(ah1, b21.lo, acc2);
            acc3 = MFMA16(ah0, b30.lo, acc3); acc3 = MFMA16(ah1, b31.lo, acc3);
            // write gate preacts: C/D row = quad*4+r (seq), col = u_m (unit)
#pragma unroll
            for (int r = 0; r < 4; ++r) {
                gt[0][quad * 4 + r][u_m] = acc0[r];
                gt[1][quad * 4 + r][u_m] = acc1[r];
                gt[2][quad * 4 + r][u_m] = acc2[r];
                gt[3][quad * 4 + r][u_m] = acc3[r];
            }
        } else if (tt == 0 && t + 64 < TSTEPS) {
            // epi waves stage the next chunk (read 64 steps from now)
            int nc = (t >> 6) + 1;
            bsh8 (*dst)[SPB] = xb[nc & 1];
            int t0n = nc * 64;
#pragma unroll
            for (int it = 0; it < 4; ++it) {
                int idx = (tid - 256) + it * 256;
                int t2  = idx >> 4;
                int s   = idx & 15;
                const float* xp = feat + (size_t)(seq0 + s) * (TSTEPS * FIN)
                                       + (t0n + t2) * FIN;
                bsh8 v = {0, 0, 0, 0, 0, 0, 0, 0};
#pragma unroll
                for (int j = 0; j < FIN; ++j) v[j] = (short)bf16hi_rn(xp[j]);
                dst[t2][s] = v;
            }
        }
        __syncthreads();   // gates ready

        // ---- phase 2 ----
        if (is_m) {
            if (t < TSTEPS - 1) {   // x-part of step t+1 (independent of h)
                int t1 = t + 1;
                bsh8 ax = xb[(t1 >> 6) & 1][t1 & 63][col];
                acc0 = (f32x4){0.f, 0.f, 0.f, 0.f};
                acc1 = (f32x4){0.f, 0.f, 0.f, 0.f};
                acc2 = (f32x4){0.f, 0.f, 0.f, 0.f};
                acc3 = (f32x4){0.f, 0.f, 0.f, 0.f};
                acc0 = MFMA16(ax, b02.hi, acc0); acc0 = MFMA16(ax, b02.lo, acc0);
                acc1 = MFMA16(ax, b12.hi, acc1); acc1 = MFMA16(ax, b12.lo, acc1);
                acc2 = MFMA16(ax, b22.hi, acc2); acc2 = MFMA16(ax, b22.lo, acc2);
                acc3 = MFMA16(ax, b32.hi, acc3); acc3 = MFMA16(ax, b32.lo, acc3);
            }
        } else {
            // epi wave e: unit = lane, seqs 4e..4e+3
#pragma unroll
            for (int r = 0; r < 4; ++r) {
                int s = 4 * e + r;
                float gi = fast_sigmoid(gt[0][s][lane] + bi);
                float gf = fast_sigmoid(gt[1][s][lane] + bf_);
                float gg = fast_tanh  (gt[2][s][lane] + bg);
                float go = fast_sigmoid(gt[3][s][lane] + bo);
                c_[r] = gf * c_[r] + gi * gg;
                float hh = go * fast_tanh(c_[r]);
                ((unsigned short*)&aA[nb][s][0])[lane] = bf16hi_rn(hh);
                if (t == TSTEPS - 1) hf[s][lane] = hh;
            }
        }
        __syncthreads();   // h(t) (and staged x) visible
    }

    // ---- fused pred head: pred = leaky_relu(h @ Wd^T + bd) ----
    if (tid < 256) {
        int s  = tid & 15;
        int q4 = tid >> 4;           // 16 unit-groups of 4
        int j0 = q4 * 4;
        float part = hf[s][j0] * Wd[j0] + hf[s][j0 + 1] * Wd[j0 + 1]
                   + hf[s][j0 + 2] * Wd[j0 + 2] + hf[s][j0 + 3] * Wd[j0 + 3];
        pf[s][q4] = part;
    }
    __syncthreads();
    if (tid < SPB) {
        float sum = bd[0];
#pragma unroll
        for (int j = 0; j < 16; ++j) sum += pf[tid][j];
        float p = (sum >= 0.0f) ? sum : 0.2f * sum;
        pred[seq0 + tid] = p;
    }
}

// fused losses: every block does a 16-i rank slice; block 0 also does reg MSE
__global__ __launch_bounds__(256)
void loss_kernel(const float* __restrict__ pred,
                 const float* __restrict__ ret,
                 const int* __restrict__ mask,
                 float* __restrict__ accums) {
    __shared__ float sp[NSEQ];
    __shared__ float sg[NSEQ];
    __shared__ float sq[NSEQ];
    int tid = threadIdx.x;
    for (int idx = tid; idx < NSEQ; idx += 256) {
        sp[idx] = pred[idx];
        sg[idx] = ret[idx];
        sq[idx] = (mask[idx] != 0) ? 1.0f : 0.0f;
    }
    __syncthreads();

    if (blockIdx.x == 0) {   // regression loss partials
        float v = 0.0f, m = 0.0f;
        for (int j = tid; j < NSEQ; j += 256) {
            float mj = sq[j];
            float d  = sp[j] - sg[j];
            v += d * d * mj;
            m += mj;
        }
#pragma unroll
        for (int off = 32; off > 0; off >>= 1) {
            v += __shfl_down(v, off, 64);
            m += __shfl_down(m, off, 64);
        }
        if ((tid & 63) == 0) {
            atomicAdd(&accums[0], v);
            atomicAdd(&accums[1], m);
        }
    }

    int iloc = tid >> 4;
    int jp   = tid & 15;
    int i    = blockIdx.x * 16 + iloc;
    float pi = sp[i], gi = sg[i], qi = sq[i];
    float sum = 0.0f;
    for (int j = jp; j < NSEQ; j += 16) {
        float t = -(sp[j] - pi) * (sg[j] - gi);
        sum += fmaxf(t, 0.0f) * sq[j];
    }
    sum *= qi;
#pragma unroll
    for (int off = 32; off > 0; off >>= 1) sum += __shfl_down(sum, off, 64);
    __shared__ float wsum[4];
    if ((tid & 63) == 0) wsum[tid >> 6] = sum;
    __syncthreads();
    if (tid == 0) atomicAdd(&accums[2], wsum[0] + wsum[1] + wsum[2] + wsum[3]);
}

__global__ void final_kernel(const float* __restrict__ accums,
                             float* __restrict__ out) {
    float reg  = accums[0] / (accums[1] + 1e-8f);
    float rank = accums[2] / 16777216.0f;   // N*N
    out[NSEQ + 0] = reg + rank;
    out[NSEQ + 1] = reg;
    out[NSEQ + 2] = rank;
}

extern "C" void kernel_launch(void* const* d_in, const int* in_sizes, int n_in,
                              void* d_out, int out_size, void* d_ws, size_t ws_size,
                              hipStream_t stream) {
    const float* feat = (const float*)d_in[0];
    const float* ret  = (const float*)d_in[1];
    const int*   mask = (const int*)d_in[2];
    const float* Wih  = (const float*)d_in[3];
    const float* Whh  = (const float*)d_in[4];
    const float* bih  = (const float*)d_in[5];
    const float* bhh  = (const float*)d_in[6];
    const float* Wd   = (const float*)d_in[7];
    const float* bd   = (const float*)d_in[8];
    float* out    = (float*)d_out;
    float* accums = (float*)d_ws;            // [0..3] loss partials

    lstm_kernel<<<NSEQ / SPB, BLK, 0, stream>>>(feat, Wih, Whh, bih, bhh,
                                                Wd, bd, out, accums);
    loss_kernel<<<NSEQ / 16, 256, 0, stream>>>(out, ret, mask, accums);
    final_kernel<<<1, 1, 0, stream>>>(accums, out);
}

// Round 9
// 508.878 us; speedup vs baseline: 1.0993x; 1.0993x over previous
//
#include <hip/hip_runtime.h>

#define NSEQ   4096
#define TSTEPS 512
#define FIN    5
#define HID    64
#define SPB    16     // sequences per block (MFMA M)
#define BLK    512    // 8 symmetric waves = 2/SIMD (R8 lesson: no asymmetric roles)

// Neutral names — do NOT reuse HIP vector-type names like short8 (R4 crash)
typedef __attribute__((ext_vector_type(8))) short bsh8;    // 8 bf16 in 4 VGPRs
typedef __attribute__((ext_vector_type(4))) float f32x4;   // MFMA accumulator

#define MFMA16(A, B, C) __builtin_amdgcn_mfma_f32_16x16x32_bf16((A), (B), (C), 0, 0, 0)

struct Frag2 { bsh8 hi; bsh8 lo; };

__device__ __forceinline__ unsigned short bf16hi_rn(float x) {
    unsigned u = __float_as_uint(x);
    return (unsigned short)((u + 0x7fffu + ((u >> 16) & 1u)) >> 16);
}
__device__ __forceinline__ void split_bf16(float v, unsigned short& h, unsigned short& l) {
    h = bf16hi_rn(v);
    float hf = __uint_as_float(((unsigned)h) << 16);
    l = bf16hi_rn(v - hf);
}

__device__ __forceinline__ float fast_sigmoid(float x) {
    return __builtin_amdgcn_rcpf(1.0f + __expf(-x));
}
__device__ __forceinline__ float fast_tanh(float x) {
    return 1.0f - 2.0f * __builtin_amdgcn_rcpf(1.0f + __expf(2.0f * x));
}

// B-fragment (weights SPLIT hi/lo — systematic weight error stays ~2^-17)
__device__ __forceinline__ Frag2 load_whh_frag(const float* __restrict__ Whh, int gate, int k) {
    const float* p = Whh + gate * HID + k;
    Frag2 r;
#pragma unroll
    for (int j = 0; j < 8; ++j) {
        unsigned short h, l;
        split_bf16(p[j], h, l);
        r.hi[j] = (short)h; r.lo[j] = (short)l;
    }
    return r;
}
__device__ __forceinline__ Frag2 load_wih_frag(const float* __restrict__ Wih, int gate, int quad) {
    Frag2 r;
#pragma unroll
    for (int j = 0; j < 8; ++j) { r.hi[j] = 0; r.lo[j] = 0; }
    if (quad == 0) {
#pragma unroll
        for (int j = 0; j < FIN; ++j) {
            unsigned short h, l;
            split_bf16(Wih[gate * FIN + j], h, l);
            r.hi[j] = (short)h; r.lo[j] = (short)l;
        }
    }
    return r;
}

// Symmetric 8-wave MFMA LSTM. Wave (u4 = w&3, half = w>>2) computes 2 gate
// classes (half 0: i,f; half 1: g,o) for units [16u4,16u4+16) -> 12 MFMA/wave,
// total 96 = R6's work, NO duplication (R7 lesson) and NO role asymmetry (R8
// lesson). Epilogue split by C-rows: half 0 -> rows {0,1}, half 1 -> {2,3};
// the 2 foreign gates per cell cross via a small fp32 LDS exchange. Two waves
// per SIMD fill each other's dependency stalls; per-SIMD VALU issue unchanged.
__global__ __launch_bounds__(BLK)
void lstm_kernel(const float* __restrict__ feat,
                 const float* __restrict__ Wih,
                 const float* __restrict__ Whh,
                 const float* __restrict__ bih,
                 const float* __restrict__ bhh,
                 const float* __restrict__ Wd,
                 const float* __restrict__ bd,
                 float* __restrict__ pred,
                 float* __restrict__ accums) {
    __shared__ bsh8  aA[2][SPB][9];        // h bf16, double-buffered (4.6 KB)
    __shared__ bsh8  xb[2][64][SPB];       // x bf16, chunk double buffer (32 KB)
    __shared__ float xg[4][SPB][HID + 1];  // gate-preact exchange (16.6 KB)
    __shared__ float hf[SPB][HID + 1];     // final h fp32 for pred tail
    __shared__ float pf[SPB][17];          // pred partials

    const int tid  = threadIdx.x;
    const int w    = tid >> 6;             // wave 0..7
    const int lane = tid & 63;
    const int col  = lane & 15;            // MFMA col / A-row (seq)
    const int quad = lane >> 4;
    const int u4   = w & 3;                // unit group
    const int half = w >> 2;               // 0: gates i,f; 1: gates g,o
    const int u    = 16 * u4 + col;        // unit handled by this lane
    const int seq0 = blockIdx.x * SPB;
    const int ro   = 2 * half;             // own epilogue rows ro, ro+1
    const int fo   = 2 - 2 * half;         // foreign rows (partner handles)

    if (blockIdx.x == 0 && tid < 4) accums[tid] = 0.0f;   // loss accumulators

    // ---- persistent B fragments: 2 gate classes (named — R1/R2 spill lessons) ----
    const int gA = (2 * half + 0) * HID + u;
    const int gB = (2 * half + 1) * HID + u;
    Frag2 bA0 = load_whh_frag(Whh, gA, quad * 8);
    Frag2 bA1 = load_whh_frag(Whh, gA, 32 + quad * 8);
    Frag2 bA2 = load_wih_frag(Wih, gA, quad);
    Frag2 bB0 = load_whh_frag(Whh, gB, quad * 8);
    Frag2 bB1 = load_whh_frag(Whh, gB, 32 + quad * 8);
    Frag2 bB2 = load_wih_frag(Wih, gB, quad);

    const float bsA = bih[gA] + bhh[gA];
    const float bsB = bih[gB] + bhh[gB];

    // zero h buffer 0 (144 vectors)
    {
        bsh8 z = {0, 0, 0, 0, 0, 0, 0, 0};
        if (tid < SPB * 9) (&aA[0][0][0])[tid] = z;
    }
    // stage chunk 0 (all 512 threads)
#pragma unroll
    for (int it = 0; it < (64 * SPB) / BLK; ++it) {
        int idx = tid + it * BLK;
        int t2  = idx >> 4;
        int s   = idx & 15;
        const float* xp = feat + (size_t)(seq0 + s) * (TSTEPS * FIN) + t2 * FIN;
        bsh8 v = {0, 0, 0, 0, 0, 0, 0, 0};
#pragma unroll
        for (int j = 0; j < FIN; ++j) v[j] = (short)bf16hi_rn(xp[j]);
        xb[0][t2][s] = v;
    }
    __syncthreads();

    // acc := bias + x-part of step 0 (4 MFMAs)
    f32x4 accA = {bsA, bsA, bsA, bsA};
    f32x4 accB = {bsB, bsB, bsB, bsB};
    {
        bsh8 ax = xb[0][0][col];
        accA = MFMA16(ax, bA2.hi, accA); accA = MFMA16(ax, bA2.lo, accA);
        accB = MFMA16(ax, bB2.hi, accB); accB = MFMA16(ax, bB2.lo, accB);
    }

    float c_[2] = {0.f, 0.f};   // own rows ro, ro+1 (per quad: seq quad*4+ro+j)

    for (int t = 0; t < TSTEPS; ++t) {
        const int tt  = t & 63;
        const int buf = t & 1;
        const int nb  = buf ^ 1;

        // ---- phase 1: 8 h-MFMAs, then export foreign-row preacts ----
        bsh8 ah0 = aA[buf][col][quad];
        bsh8 ah1 = aA[buf][col][4 + quad];
        accA = MFMA16(ah0, bA0.hi, accA); accA = MFMA16(ah1, bA1.hi, accA);
        accB = MFMA16(ah0, bB0.hi, accB); accB = MFMA16(ah1, bB1.hi, accB);
        accA = MFMA16(ah0, bA0.lo, accA); accA = MFMA16(ah1, bA1.lo, accA);
        accB = MFMA16(ah0, bB0.lo, accB); accB = MFMA16(ah1, bB1.lo, accB);

        xg[2 * half + 0][quad * 4 + fo + 0][u] = accA[fo + 0];
        xg[2 * half + 0][quad * 4 + fo + 1][u] = accA[fo + 1];
        xg[2 * half + 1][quad * 4 + fo + 0][u] = accB[fo + 0];
        xg[2 * half + 1][quad * 4 + fo + 1][u] = accB[fo + 1];
        __syncthreads();   // exchange visible

        // ---- phase 2: stage (1/64 steps), epilogue own rows, x-MFMA t+1 ----
        if (tt == 0 && t + 64 < TSTEPS) {
            int nc  = (t >> 6) + 1;
            int t0n = nc * 64;
            bsh8 (*dst)[SPB] = xb[nc & 1];
#pragma unroll
            for (int it = 0; it < (64 * SPB) / BLK; ++it) {
                int idx = tid + it * BLK;
                int t2  = idx >> 4;
                int s   = idx & 15;
                const float* xp = feat + (size_t)(seq0 + s) * (TSTEPS * FIN)
                                       + (t0n + t2) * FIN;
                bsh8 v = {0, 0, 0, 0, 0, 0, 0, 0};
#pragma unroll
                for (int j = 0; j < FIN; ++j) v[j] = (short)bf16hi_rn(xp[j]);
                dst[t2][s] = v;
            }
        }

#pragma unroll
        for (int j = 0; j < 2; ++j) {
            const int r = ro + j;
            const int s = quad * 4 + r;
            float vi, vf, vg, vo;
            if (half == 0) {
                vi = accA[r];      vf = accB[r];
                vg = xg[2][s][u];  vo = xg[3][s][u];
            } else {
                vi = xg[0][s][u];  vf = xg[1][s][u];
                vg = accA[r];      vo = accB[r];
            }
            float gi = fast_sigmoid(vi);
            float gf = fast_sigmoid(vf);
            float gg = fast_tanh  (vg);
            float go = fast_sigmoid(vo);
            c_[j] = gf * c_[j] + gi * gg;
            float hh = go * fast_tanh(c_[j]);
            ((unsigned short*)&aA[nb][s][0])[u] = bf16hi_rn(hh);
            if (t == TSTEPS - 1) hf[s][u] = hh;
        }

        if (t < TSTEPS - 1) {   // x-part of step t+1 (independent of h)
            int t1 = t + 1;
            bsh8 ax = xb[(t1 >> 6) & 1][t1 & 63][col];
            accA = (f32x4){bsA, bsA, bsA, bsA};
            accB = (f32x4){bsB, bsB, bsB, bsB};
            accA = MFMA16(ax, bA2.hi, accA); accA = MFMA16(ax, bA2.lo, accA);
            accB = MFMA16(ax, bB2.hi, accB); accB = MFMA16(ax, bB2.lo, accB);
        }
        __syncthreads();   // h(t), staged x visible; xg safe to overwrite
    }

    // ---- fused pred head: pred = leaky_relu(h @ Wd^T + bd) ----
    if (tid < 256) {
        int s  = tid & 15;
        int q4 = tid >> 4;           // 16 unit-groups of 4
        int j0 = q4 * 4;
        float part = hf[s][j0] * Wd[j0] + hf[s][j0 + 1] * Wd[j0 + 1]
                   + hf[s][j0 + 2] * Wd[j0 + 2] + hf[s][j0 + 3] * Wd[j0 + 3];
        pf[s][q4] = part;
    }
    __syncthreads();
    if (tid < SPB) {
        float sum = bd[0];
#pragma unroll
        for (int j = 0; j < 16; ++j) sum += pf[tid][j];
        float p = (sum >= 0.0f) ? sum : 0.2f * sum;
        pred[seq0 + tid] = p;
    }
}

// fused losses: every block does a 16-i rank slice; block 0 also does reg MSE
__global__ __launch_bounds__(256)
void loss_kernel(const float* __restrict__ pred,
                 const float* __restrict__ ret,
                 const int* __restrict__ mask,
                 float* __restrict__ accums) {
    __shared__ float sp[NSEQ];
    __shared__ float sg[NSEQ];
    __shared__ float sq[NSEQ];
    int tid = threadIdx.x;
    for (int idx = tid; idx < NSEQ; idx += 256) {
        sp[idx] = pred[idx];
        sg[idx] = ret[idx];
        sq[idx] = (mask[idx] != 0) ? 1.0f : 0.0f;
    }
    __syncthreads();

    if (blockIdx.x == 0) {   // regression loss partials
        float v = 0.0f, m = 0.0f;
        for (int j = tid; j < NSEQ; j += 256) {
            float mj = sq[j];
            float d  = sp[j] - sg[j];
            v += d * d * mj;
            m += mj;
        }
#pragma unroll
        for (int off = 32; off > 0; off >>= 1) {
            v += __shfl_down(v, off, 64);
            m += __shfl_down(m, off, 64);
        }
        if ((tid & 63) == 0) {
            atomicAdd(&accums[0], v);
            atomicAdd(&accums[1], m);
        }
    }

    int iloc = tid >> 4;
    int jp   = tid & 15;
    int i    = blockIdx.x * 16 + iloc;
    float pi = sp[i], gi = sg[i], qi = sq[i];
    float sum = 0.0f;
    for (int j = jp; j < NSEQ; j += 16) {
        float t = -(sp[j] - pi) * (sg[j] - gi);
        sum += fmaxf(t, 0.0f) * sq[j];
    }
    sum *= qi;
#pragma unroll
    for (int off = 32; off > 0; off >>= 1) sum += __shfl_down(sum, off, 64);
    __shared__ float wsum[4];
    if ((tid & 63) == 0) wsum[tid >> 6] = sum;
    __syncthreads();
    if (tid == 0) atomicAdd(&accums[2], wsum[0] + wsum[1] + wsum[2] + wsum[3]);
}

__global__ void final_kernel(const float* __restrict__ accums,
                             float* __restrict__ out) {
    float reg  = accums[0] / (accums[1] + 1e-8f);
    float rank = accums[2] / 16777216.0f;   // N*N
    out[NSEQ + 0] = reg + rank;
    out[NSEQ + 1] = reg;
    out[NSEQ + 2] = rank;
}

extern "C" void kernel_launch(void* const* d_in, const int* in_sizes, int n_in,
                              void* d_out, int out_size, void* d_ws, size_t ws_size,
                              hipStream_t stream) {
    const float* feat = (const float*)d_in[0];
    const float* ret  = (const float*)d_in[1];
    const int*   mask = (const int*)d_in[2];
    const float* Wih  = (const float*)d_in[3];
    const float* Whh  = (const float*)d_in[4];
    const float* bih  = (const float*)d_in[5];
    const float* bhh  = (const float*)d_in[6];
    const float* Wd   = (const float*)d_in[7];
    const float* bd   = (const float*)d_in[8];
    float* out    = (float*)d_out;
    float* accums = (float*)d_ws;            // [0..3] loss partials

    lstm_kernel<<<NSEQ / SPB, BLK, 0, stream>>>(feat, Wih, Whh, bih, bhh,
                                                Wd, bd, out, accums);
    loss_kernel<<<NSEQ / 16, 256, 0, stream>>>(out, ret, mask, accums);
    final_kernel<<<1, 1, 0, stream>>>(accums, out);
}